// Round 6
// baseline (273.002 us; speedup 1.0000x reference)
//
#include <hip/hip_runtime.h>
#include <hip/hip_bf16.h>

#define NBT 8192      // B*T
#define NF  16
#define ND  256
#define NH  256
#define N2D 512

typedef short bf16x8 __attribute__((ext_vector_type(8)));
typedef float f32x4 __attribute__((ext_vector_type(4)));
typedef unsigned short u16x8 __attribute__((ext_vector_type(8)));

__device__ __forceinline__ float bf2f(unsigned short u) {
  return __uint_as_float(((unsigned)u) << 16);
}
__device__ __forceinline__ unsigned short f2bf(float f) {
  unsigned u = __float_as_uint(f);
  return (unsigned short)((u + 0x7FFFu + ((u >> 16) & 1u)) >> 16);
}

// ---------------------------------------------------------------------------
// Weight GRN + softmax -> w [NBT][16] (fp32 exact; validated round 1)
// ---------------------------------------------------------------------------
__global__ __launch_bounds__(256) void wgrn_kernel(
    const float* __restrict__ x, const float* __restrict__ fw1,
    const float* __restrict__ fb1, const float* __restrict__ fw2,
    const float* __restrict__ fb2, const float* __restrict__ gwt,
    const float* __restrict__ gbt, const float* __restrict__ lng,
    const float* __restrict__ lnb, float* __restrict__ wout) {
  __shared__ float w1t[256 * 16];
  __shared__ float w2s[256 * 16];
  const int tid = threadIdx.x;
  for (int i = tid; i < 4096; i += 256) {
    int ff = i >> 8, j = i & 255;
    w1t[j * 16 + ff] = fw1[i];
    w2s[i] = fw2[i];
  }
  __syncthreads();
  const int sub  = tid & 7;
  const int rowi = tid >> 3;
  const int bt   = blockIdx.x * 32 + rowi;
  float xr[16];
#pragma unroll
  for (int i = 0; i < 4; ++i)
    *(float4*)&xr[i * 4] = *(const float4*)(x + (size_t)bt * 16 + i * 4);
  float acc2[16];
#pragma unroll
  for (int q = 0; q < 16; ++q) acc2[q] = 0.f;
  for (int j = sub; j < 256; j += 8) {
    float h = fb1[j];
    const float* wr = &w1t[j * 16];
#pragma unroll
    for (int q = 0; q < 16; ++q) h = fmaf(xr[q], wr[q], h);
    h = h > 0.f ? h : expm1f(h);
    const float* w2r = &w2s[j * 16];
#pragma unroll
    for (int q = 0; q < 16; ++q) acc2[q] = fmaf(h, w2r[q], acc2[q]);
  }
#pragma unroll
  for (int off = 1; off < 8; off <<= 1) {
#pragma unroll
    for (int q = 0; q < 16; ++q) acc2[q] += __shfl_xor(acc2[q], off);
  }
#pragma unroll
  for (int q = 0; q < 16; ++q) acc2[q] += fb2[q];
  float gw[32];
#pragma unroll
  for (int k = 0; k < 32; ++k) {
    float s = gbt[k];
#pragma unroll
    for (int q = 0; q < 16; ++q) s = fmaf(acc2[q], gwt[q * 32 + k], s);
    gw[k] = s;
  }
  float v[16];
  float mean = 0.f;
#pragma unroll
  for (int q = 0; q < 16; ++q) {
    float sg = 1.f / (1.f + __expf(-gw[16 + q]));
    v[q] = fmaf(gw[q], sg, xr[q]);
    mean += v[q];
  }
  mean *= (1.f / 16.f);
  float var = 0.f;
#pragma unroll
  for (int q = 0; q < 16; ++q) { float d = v[q] - mean; var = fmaf(d, d, var); }
  var *= (1.f / 16.f);
  float rstd = rsqrtf(var + 1e-5f);
  float mx = -1e30f;
#pragma unroll
  for (int q = 0; q < 16; ++q) {
    v[q] = (v[q] - mean) * rstd * lng[q] + lnb[q];
    mx = fmaxf(mx, v[q]);
  }
  float se = 0.f;
#pragma unroll
  for (int q = 0; q < 16; ++q) { v[q] = __expf(v[q] - mx); se += v[q]; }
  float inv = 1.f / se;
  if (sub == 0) {
#pragma unroll
    for (int i = 0; i < 4; ++i) {
      float4 o = { v[i*4+0]*inv, v[i*4+1]*inv, v[i*4+2]*inv, v[i*4+3]*inv };
      *(float4*)(wout + (size_t)bt * 16 + i * 4) = o;
    }
  }
}

// ---------------------------------------------------------------------------
// Fused weight prep: fp32 [K][N] -> bf16 [N][K] (validated round 5)
// ---------------------------------------------------------------------------
__global__ void transpose_all(const float* __restrict__ fc1_w,
                              const float* __restrict__ fc2_w,
                              const float* __restrict__ glu_w,
                              unsigned short* __restrict__ fc1t,
                              unsigned short* __restrict__ fc2t,
                              unsigned short* __restrict__ glut) {
  __shared__ float tile[32][33];
  const int which = blockIdx.z >> 4;
  const int f     = blockIdx.z & 15;
  const float* src;
  unsigned short* dst;
  int K, N, bx = blockIdx.x;
  if (which == 0)      { src = fc1_w; dst = fc1t; K = ND; N = NH; }
  else if (which == 1) { src = fc2_w; dst = fc2t; K = NH; N = ND; }
  else                 { src = glu_w; dst = glut; K = ND; N = N2D;
                         bx += (which == 3) ? 8 : 0; }
  if (bx * 32 >= N) return;
  const float* s = src + (size_t)f * K * N;
  unsigned short* d = dst + (size_t)f * K * N;
  const int k0 = blockIdx.y * 32, n0 = bx * 32;
  const int tx = threadIdx.x, ty = threadIdx.y;
#pragma unroll
  for (int i = 0; i < 32; i += 8)
    tile[ty + i][tx] = s[(size_t)(k0 + ty + i) * N + n0 + tx];
  __syncthreads();
#pragma unroll
  for (int i = 0; i < 32; i += 8)
    d[(size_t)(n0 + ty + i) * K + k0 + tx] = f2bf(tile[tx][ty + i]);
}

// ---------------------------------------------------------------------------
// G1: y1 = elu(h0 @ fc1^T + b). 256 thr (4 waves, each 64 cols).
// B-frags (full K=256) in VGPR; h0 tile [64][264] computed in LDS per m-tile;
// no K-loop barriers. Bounce epilogue (validated round 4).
// ---------------------------------------------------------------------------
__global__ __launch_bounds__(256, 2) void g1_kernel(
    const float* __restrict__ x, const float* __restrict__ w1,
    const float* __restrict__ b1, const unsigned short* __restrict__ fc1t,
    const float* __restrict__ fc1_b, unsigned short* __restrict__ y1) {
  __shared__ __align__(16) unsigned short h0buf[64 * 264];
  __shared__ __align__(16) unsigned short cbuf[64 * 264];
  const int tid = threadIdx.x, lane = tid & 63, wid = tid >> 6;
  const int rl = lane & 15, kc = lane >> 4;   // kc = k-chunk AND C row-quad
  const int f = blockIdx.y;
  const unsigned short* Bf = fc1t + (size_t)f * NH * ND;  // [N][K]
  const float* w1f = w1 + f * ND;
  const float* b1f = b1 + f * ND;
  const int wn = wid * 64;

  // B-fragments: full K in registers (64 cols x 256 K = 128 VGPR)
  bf16x8 bfrag[4][8];
#pragma unroll
  for (int n = 0; n < 4; ++n)
#pragma unroll
    for (int kt = 0; kt < 8; ++kt)
      bfrag[n][kt] = *(const bf16x8*)(Bf + (size_t)(wn + n * 16 + rl) * ND +
                                      kt * 32 + kc * 8);
  float bias[4];
#pragma unroll
  for (int n = 0; n < 4; ++n) bias[n] = fc1_b[f * NH + wn + n * 16 + rl];

  // h0-writer constants: this thread always writes col chunk c8 = tid&31
  const int cc = (tid & 31) * 8;
  const float4 wva = *(const float4*)(w1f + cc);
  const float4 wvb = *(const float4*)(w1f + cc + 4);
  const float4 bva = *(const float4*)(b1f + cc);
  const float4 bvb = *(const float4*)(b1f + cc + 4);

  for (int t = 0; t < 4; ++t) {
    const int m0 = (blockIdx.x * 4 + t) * 64;
    __syncthreads();  // h0buf free (prev MFMA done), cbuf free (prev copyout)
#pragma unroll
    for (int i = 0; i < 8; ++i) {
      int row = (tid >> 5) + i * 8;
      float xv = x[(size_t)(m0 + row) * NF + f];
      u16x8 o;
      o[0] = f2bf(fmaxf(fmaf(xv, wva.x, bva.x), 0.f));
      o[1] = f2bf(fmaxf(fmaf(xv, wva.y, bva.y), 0.f));
      o[2] = f2bf(fmaxf(fmaf(xv, wva.z, bva.z), 0.f));
      o[3] = f2bf(fmaxf(fmaf(xv, wva.w, bva.w), 0.f));
      o[4] = f2bf(fmaxf(fmaf(xv, wvb.x, bvb.x), 0.f));
      o[5] = f2bf(fmaxf(fmaf(xv, wvb.y, bvb.y), 0.f));
      o[6] = f2bf(fmaxf(fmaf(xv, wvb.z, bvb.z), 0.f));
      o[7] = f2bf(fmaxf(fmaf(xv, wvb.w, bvb.w), 0.f));
      *(u16x8*)(h0buf + row * 264 + cc) = o;
    }
    __syncthreads();

    f32x4 acc[4][4];
#pragma unroll
    for (int m = 0; m < 4; ++m)
#pragma unroll
      for (int n = 0; n < 4; ++n) acc[m][n] = (f32x4){0.f, 0.f, 0.f, 0.f};
#pragma unroll
    for (int kt = 0; kt < 8; ++kt) {
      bf16x8 av[4];
#pragma unroll
      for (int m = 0; m < 4; ++m)
        av[m] = *(const bf16x8*)(h0buf + (m * 16 + rl) * 264 + kt * 32 + kc * 8);
#pragma unroll
      for (int m = 0; m < 4; ++m)
#pragma unroll
        for (int n = 0; n < 4; ++n)
          acc[m][n] = __builtin_amdgcn_mfma_f32_16x16x32_bf16(
              av[m], bfrag[n][kt], acc[m][n], 0, 0, 0);
    }

    // bounce epilogue
#pragma unroll
    for (int n = 0; n < 4; ++n) {
      int c = wn + n * 16 + rl;
#pragma unroll
      for (int m = 0; m < 4; ++m)
#pragma unroll
        for (int j = 0; j < 4; ++j) {
          int r = m * 16 + kc * 4 + j;
          float v = acc[m][n][j] + bias[n];
          v = v > 0.f ? v : expm1f(v);
          cbuf[r * 264 + c] = f2bf(v);
        }
    }
    __syncthreads();
#pragma unroll
    for (int v = 0; v < 8; ++v) {
      int job = tid + 256 * v;
      int row = job >> 5, ch = job & 31;
      u16x8 val = *(const u16x8*)(cbuf + row * 264 + ch * 8);
      *(u16x8*)(y1 + ((size_t)f * NBT + m0 + row) * NH + ch * 8) = val;
    }
  }
}

// ---------------------------------------------------------------------------
// G2: y2 = y1 @ fc2^T + b. 256 thr (4 waves x 64 cols). B-frags in VGPR,
// A-frags direct global->VGPR (no LDS staging, no K barriers).
// ---------------------------------------------------------------------------
__global__ __launch_bounds__(256, 2) void g2_kernel(
    const unsigned short* __restrict__ y1,
    const unsigned short* __restrict__ fc2t, const float* __restrict__ fc2_b,
    unsigned short* __restrict__ y2) {
  __shared__ __align__(16) unsigned short cbuf[64 * 264];
  const int tid = threadIdx.x, lane = tid & 63, wid = tid >> 6;
  const int rl = lane & 15, kc = lane >> 4;
  const int f = blockIdx.y;
  const unsigned short* Bf = fc2t + (size_t)f * ND * NH;  // [N][K]
  const int wn = wid * 64;

  bf16x8 bfrag[4][8];
#pragma unroll
  for (int n = 0; n < 4; ++n)
#pragma unroll
    for (int kt = 0; kt < 8; ++kt)
      bfrag[n][kt] = *(const bf16x8*)(Bf + (size_t)(wn + n * 16 + rl) * NH +
                                      kt * 32 + kc * 8);
  float bias[4];
#pragma unroll
  for (int n = 0; n < 4; ++n) bias[n] = fc2_b[f * ND + wn + n * 16 + rl];

  for (int t = 0; t < 4; ++t) {
    const int m0 = (blockIdx.x * 4 + t) * 64;
    const unsigned short* Ag = y1 + ((size_t)f * NBT + m0) * NH;
    f32x4 acc[4][4];
#pragma unroll
    for (int m = 0; m < 4; ++m)
#pragma unroll
      for (int n = 0; n < 4; ++n) acc[m][n] = (f32x4){0.f, 0.f, 0.f, 0.f};
#pragma unroll
    for (int kt = 0; kt < 8; ++kt) {
      bf16x8 av[4];
#pragma unroll
      for (int m = 0; m < 4; ++m)
        av[m] = *(const bf16x8*)(Ag + (size_t)(m * 16 + rl) * NH + kt * 32 +
                                 kc * 8);
#pragma unroll
      for (int m = 0; m < 4; ++m)
#pragma unroll
        for (int n = 0; n < 4; ++n)
          acc[m][n] = __builtin_amdgcn_mfma_f32_16x16x32_bf16(
              av[m], bfrag[n][kt], acc[m][n], 0, 0, 0);
    }
    if (t) __syncthreads();  // cbuf free (prev copyout done)
#pragma unroll
    for (int n = 0; n < 4; ++n) {
      int c = wn + n * 16 + rl;
#pragma unroll
      for (int m = 0; m < 4; ++m)
#pragma unroll
        for (int j = 0; j < 4; ++j) {
          int r = m * 16 + kc * 4 + j;
          cbuf[r * 264 + c] = f2bf(acc[m][n][j] + bias[n]);
        }
    }
    __syncthreads();
#pragma unroll
    for (int v = 0; v < 8; ++v) {
      int job = tid + 256 * v;
      int row = job >> 5, ch = job & 31;
      u16x8 val = *(const u16x8*)(cbuf + row * 264 + ch * 8);
      *(u16x8*)(y2 + ((size_t)f * NBT + m0 + row) * ND + ch * 8) = val;
    }
  }
}

// ---------------------------------------------------------------------------
// G3: a|gate = y2 @ glu^T + b; v = h0 + a*sig(gate); LN -> H.
// 512 thr, 8 waves; each wave owns 32 a-cols + matching 32 gate-cols
// (in-register GLU, validated round 4). B-frags (128 VGPR) in registers,
// A-frags direct global. BM=64, 8 m-tiles per block.
// ---------------------------------------------------------------------------
__global__ __launch_bounds__(512, 2) void g3_kernel(
    const unsigned short* __restrict__ y2,
    const unsigned short* __restrict__ glut, const float* __restrict__ glu_b,
    const float* __restrict__ x, const float* __restrict__ w1,
    const float* __restrict__ b1, const float* __restrict__ ln_g,
    const float* __restrict__ ln_b, unsigned short* __restrict__ H) {
  __shared__ float xw[64];
  __shared__ float2 sums[8][64];
  __shared__ float2 sums2[64];
  __shared__ __align__(16) unsigned short vbuf[64 * 264];
  const int tid = threadIdx.x, lane = tid & 63, wid = tid >> 6;
  const int rl = lane & 15, rq = lane >> 4;
  const int f = blockIdx.y;
  const unsigned short* Bf = glut + (size_t)f * ND * N2D;  // [512][256]
  const int colb = wid * 32;

  bf16x8 bfrag[4][8];
#pragma unroll
  for (int n = 0; n < 4; ++n) {
    int brow = (n < 2) ? (colb + n * 16 + rl) : (256 + colb + (n - 2) * 16 + rl);
#pragma unroll
    for (int kt = 0; kt < 8; ++kt)
      bfrag[n][kt] =
          *(const bf16x8*)(Bf + (size_t)brow * ND + kt * 32 + rq * 8);
  }
  float w1c[2], b1c[2], ab_[2], gb_[2], lg[2], lb[2];
#pragma unroll
  for (int n = 0; n < 2; ++n) {
    int cA = colb + n * 16 + rl;
    w1c[n] = w1[f * ND + cA];
    b1c[n] = b1[f * ND + cA];
    ab_[n] = glu_b[f * N2D + cA];
    gb_[n] = glu_b[f * N2D + 256 + cA];
    lg[n] = ln_g[f * ND + cA];
    lb[n] = ln_b[f * ND + cA];
  }

  for (int t = 0; t < 8; ++t) {
    const int m0 = (blockIdx.x * 8 + t) * 64;
    if (tid < 64) xw[tid] = x[(size_t)(m0 + tid) * NF + f];
    __syncthreads();
    const unsigned short* Ag = y2 + ((size_t)f * NBT + m0) * ND;
    f32x4 acc[4][4];
#pragma unroll
    for (int m = 0; m < 4; ++m)
#pragma unroll
      for (int n = 0; n < 4; ++n) acc[m][n] = (f32x4){0.f, 0.f, 0.f, 0.f};
#pragma unroll
    for (int kt = 0; kt < 8; ++kt) {
      bf16x8 av[4];
#pragma unroll
      for (int m = 0; m < 4; ++m)
        av[m] = *(const bf16x8*)(Ag + (size_t)(m * 16 + rl) * ND + kt * 32 +
                                 rq * 8);
#pragma unroll
      for (int m = 0; m < 4; ++m)
#pragma unroll
        for (int n = 0; n < 4; ++n)
          acc[m][n] = __builtin_amdgcn_mfma_f32_16x16x32_bf16(
              av[m], bfrag[n][kt], acc[m][n], 0, 0, 0);
    }
    // in-register GLU (validated round 4)
#pragma unroll
    for (int n = 0; n < 2; ++n) {
#pragma unroll
      for (int m = 0; m < 4; ++m) {
#pragma unroll
        for (int j = 0; j < 4; ++j) {
          int r = m * 16 + rq * 4 + j;
          float a = acc[m][n][j] + ab_[n];
          float g = acc[m][n + 2][j] + gb_[n];
          float sg = 1.f / (1.f + __expf(-g));
          float h0 = fmaxf(fmaf(xw[r], w1c[n], b1c[n]), 0.f);
          acc[m][n][j] = fmaf(a, sg, h0);
        }
      }
    }
    // row sums
#pragma unroll
    for (int m = 0; m < 4; ++m) {
#pragma unroll
      for (int j = 0; j < 4; ++j) {
        float s = acc[m][0][j] + acc[m][1][j];
        float q = fmaf(acc[m][0][j], acc[m][0][j],
                       acc[m][1][j] * acc[m][1][j]);
#pragma unroll
        for (int off = 1; off < 16; off <<= 1) {
          s += __shfl_xor(s, off);
          q += __shfl_xor(q, off);
        }
        if (rl == 0) sums[wid][m * 16 + rq * 4 + j] = make_float2(s, q);
      }
    }
    __syncthreads();
    if (tid < 64) {
      float tot = 0.f, tot2 = 0.f;
#pragma unroll
      for (int wv = 0; wv < 8; ++wv) {
        float2 p = sums[wv][tid];
        tot += p.x;
        tot2 += p.y;
      }
      float mean = tot * (1.f / 256.f);
      float var  = tot2 * (1.f / 256.f) - mean * mean;
      sums2[tid] = make_float2(mean, rsqrtf(var + 1e-5f));
    }
    __syncthreads();
#pragma unroll
    for (int n = 0; n < 2; ++n) {
      int cA = colb + n * 16 + rl;
#pragma unroll
      for (int m = 0; m < 4; ++m) {
#pragma unroll
        for (int j = 0; j < 4; ++j) {
          int r = m * 16 + rq * 4 + j;
          float2 mr = sums2[r];
          vbuf[r * 264 + cA] =
              f2bf(fmaf((acc[m][n][j] - mr.x) * mr.y, lg[n], lb[n]));
        }
      }
    }
    __syncthreads();
#pragma unroll
    for (int v = 0; v < 4; ++v) {
      int job = tid + 512 * v;
      int row = job >> 5, ch = job & 31;
      u16x8 val = *(const u16x8*)(vbuf + row * 264 + ch * 8);
      *(u16x8*)(H + ((size_t)f * NBT + m0 + row) * ND + ch * 8) = val;
    }
  }
}

// ---------------------------------------------------------------------------
// z[bt][d] = sum_f H[f][bt][d] * w[bt][f]  (validated round 1)
// ---------------------------------------------------------------------------
__global__ __launch_bounds__(256) void combine_kernel(
    const unsigned short* __restrict__ H, const float* __restrict__ w,
    float* __restrict__ z) {
  int idx = blockIdx.x * 256 + threadIdx.x;
  int bt = idx >> 5;
  int d  = (idx & 31) << 3;
  float a[8];
#pragma unroll
  for (int j = 0; j < 8; ++j) a[j] = 0.f;
#pragma unroll
  for (int f = 0; f < 16; ++f) {
    u16x8 hv = *(const u16x8*)(H + ((size_t)f * NBT + bt) * ND + d);
    float wvv = w[bt * 16 + f];
#pragma unroll
    for (int j = 0; j < 8; ++j) a[j] = fmaf(bf2f(hv[j]), wvv, a[j]);
  }
  float4 o0 = {a[0], a[1], a[2], a[3]};
  float4 o1 = {a[4], a[5], a[6], a[7]};
  *(float4*)(z + (size_t)bt * ND + d)     = o0;
  *(float4*)(z + (size_t)bt * ND + d + 4) = o1;
}

// ---------------------------------------------------------------------------
extern "C" void kernel_launch(void* const* d_in, const int* in_sizes, int n_in,
                              void* d_out, int out_size, void* d_ws,
                              size_t ws_size, hipStream_t stream) {
  const float* x        = (const float*)d_in[0];
  const float* w1       = (const float*)d_in[1];
  const float* b1       = (const float*)d_in[2];
  const float* fc1_w    = (const float*)d_in[3];
  const float* fc1_b    = (const float*)d_in[4];
  const float* fc2_w    = (const float*)d_in[5];
  const float* fc2_b    = (const float*)d_in[6];
  const float* glu_w    = (const float*)d_in[7];
  const float* glu_b    = (const float*)d_in[8];
  const float* ln_g     = (const float*)d_in[9];
  const float* ln_b     = (const float*)d_in[10];
  const float* wg_fc1_w = (const float*)d_in[11];
  const float* wg_fc1_b = (const float*)d_in[12];
  const float* wg_fc2_w = (const float*)d_in[13];
  const float* wg_fc2_b = (const float*)d_in[14];
  const float* wg_glu_w = (const float*)d_in[15];
  const float* wg_glu_b = (const float*)d_in[16];
  const float* wg_ln_g  = (const float*)d_in[17];
  const float* wg_ln_b  = (const float*)d_in[18];

  char* ws = (char*)d_ws;
  unsigned short* fc1t = (unsigned short*)ws;                       // 2 MB
  unsigned short* fc2t = fc1t + (size_t)NF * NH * ND;               // 2 MB
  unsigned short* glut = fc2t + (size_t)NF * ND * NH;               // 4 MB
  unsigned short* y1   = (unsigned short*)(ws + (8ull << 20));      // 64 MiB
  unsigned short* y2   = (unsigned short*)(ws + (72ull << 20));     // 64 MiB
  unsigned short* Hbuf = (unsigned short*)(ws + (136ull << 20));    // 64 MiB

  float* zout = (float*)d_out;                 // [NBT][ND]
  float* wout = zout + (size_t)NBT * ND;       // [NBT][16]

  wgrn_kernel<<<256, 256, 0, stream>>>(x, wg_fc1_w, wg_fc1_b, wg_fc2_w,
                                       wg_fc2_b, wg_glu_w, wg_glu_b, wg_ln_g,
                                       wg_ln_b, wout);
  transpose_all<<<dim3(16, 8, 64), dim3(32, 8), 0, stream>>>(
      fc1_w, fc2_w, glu_w, fc1t, fc2t, glut);

  g1_kernel<<<dim3(32, 16), 256, 0, stream>>>(x, w1, b1, fc1t, fc1_b, y1);
  g2_kernel<<<dim3(32, 16), 256, 0, stream>>>(y1, fc2t, fc2_b, y2);
  g3_kernel<<<dim3(16, 16), 512, 0, stream>>>(y2, glut, glu_b, x, w1, b1,
                                              ln_g, ln_b, Hbuf);
  combine_kernel<<<(NBT * ND / 8) / 256, 256, 0, stream>>>(Hbuf, wout, zout);

  (void)in_sizes; (void)n_in; (void)out_size; (void)ws_size;
}

// Round 7
// 265.398 us; speedup vs baseline: 1.0287x; 1.0287x over previous
//
#include <hip/hip_runtime.h>
#include <hip/hip_bf16.h>

#define NBT 8192      // B*T
#define NF  16
#define ND  256
#define NH  256
#define N2D 512

typedef short bf16x8 __attribute__((ext_vector_type(8)));
typedef float f32x4 __attribute__((ext_vector_type(4)));
typedef unsigned short u16x8 __attribute__((ext_vector_type(8)));

__device__ __forceinline__ float bf2f(unsigned short u) {
  return __uint_as_float(((unsigned)u) << 16);
}
__device__ __forceinline__ unsigned short f2bf(float f) {
  unsigned u = __float_as_uint(f);
  return (unsigned short)((u + 0x7FFFu + ((u >> 16) & 1u)) >> 16);
}

#define GLOAD16(src, dst)                                                     \
  __builtin_amdgcn_global_load_lds(                                           \
      (const __attribute__((address_space(1))) unsigned int*)(src),           \
      (__attribute__((address_space(3))) unsigned int*)(dst), 16, 0, 0)

// ---------------------------------------------------------------------------
// Weight GRN + softmax -> w [NBT][16] (fp32 exact; validated round 1)
// ---------------------------------------------------------------------------
__global__ __launch_bounds__(256) void wgrn_kernel(
    const float* __restrict__ x, const float* __restrict__ fw1,
    const float* __restrict__ fb1, const float* __restrict__ fw2,
    const float* __restrict__ fb2, const float* __restrict__ gwt,
    const float* __restrict__ gbt, const float* __restrict__ lng,
    const float* __restrict__ lnb, float* __restrict__ wout) {
  __shared__ float w1t[256 * 16];
  __shared__ float w2s[256 * 16];
  const int tid = threadIdx.x;
  for (int i = tid; i < 4096; i += 256) {
    int ff = i >> 8, j = i & 255;
    w1t[j * 16 + ff] = fw1[i];
    w2s[i] = fw2[i];
  }
  __syncthreads();
  const int sub  = tid & 7;
  const int rowi = tid >> 3;
  const int bt   = blockIdx.x * 32 + rowi;
  float xr[16];
#pragma unroll
  for (int i = 0; i < 4; ++i)
    *(float4*)&xr[i * 4] = *(const float4*)(x + (size_t)bt * 16 + i * 4);
  float acc2[16];
#pragma unroll
  for (int q = 0; q < 16; ++q) acc2[q] = 0.f;
  for (int j = sub; j < 256; j += 8) {
    float h = fb1[j];
    const float* wr = &w1t[j * 16];
#pragma unroll
    for (int q = 0; q < 16; ++q) h = fmaf(xr[q], wr[q], h);
    h = h > 0.f ? h : expm1f(h);
    const float* w2r = &w2s[j * 16];
#pragma unroll
    for (int q = 0; q < 16; ++q) acc2[q] = fmaf(h, w2r[q], acc2[q]);
  }
#pragma unroll
  for (int off = 1; off < 8; off <<= 1) {
#pragma unroll
    for (int q = 0; q < 16; ++q) acc2[q] += __shfl_xor(acc2[q], off);
  }
#pragma unroll
  for (int q = 0; q < 16; ++q) acc2[q] += fb2[q];
  float gw[32];
#pragma unroll
  for (int k = 0; k < 32; ++k) {
    float s = gbt[k];
#pragma unroll
    for (int q = 0; q < 16; ++q) s = fmaf(acc2[q], gwt[q * 32 + k], s);
    gw[k] = s;
  }
  float v[16];
  float mean = 0.f;
#pragma unroll
  for (int q = 0; q < 16; ++q) {
    float sg = 1.f / (1.f + __expf(-gw[16 + q]));
    v[q] = fmaf(gw[q], sg, xr[q]);
    mean += v[q];
  }
  mean *= (1.f / 16.f);
  float var = 0.f;
#pragma unroll
  for (int q = 0; q < 16; ++q) { float d = v[q] - mean; var = fmaf(d, d, var); }
  var *= (1.f / 16.f);
  float rstd = rsqrtf(var + 1e-5f);
  float mx = -1e30f;
#pragma unroll
  for (int q = 0; q < 16; ++q) {
    v[q] = (v[q] - mean) * rstd * lng[q] + lnb[q];
    mx = fmaxf(mx, v[q]);
  }
  float se = 0.f;
#pragma unroll
  for (int q = 0; q < 16; ++q) { v[q] = __expf(v[q] - mx); se += v[q]; }
  float inv = 1.f / se;
  if (sub == 0) {
#pragma unroll
    for (int i = 0; i < 4; ++i) {
      float4 o = { v[i*4+0]*inv, v[i*4+1]*inv, v[i*4+2]*inv, v[i*4+3]*inv };
      *(float4*)(wout + (size_t)bt * 16 + i * 4) = o;
    }
  }
}

// ---------------------------------------------------------------------------
// Fused weight prep: fp32 [K][N] -> bf16 [N][K] (validated round 5)
// ---------------------------------------------------------------------------
__global__ void transpose_all(const float* __restrict__ fc1_w,
                              const float* __restrict__ fc2_w,
                              const float* __restrict__ glu_w,
                              unsigned short* __restrict__ fc1t,
                              unsigned short* __restrict__ fc2t,
                              unsigned short* __restrict__ glut) {
  __shared__ float tile[32][33];
  const int which = blockIdx.z >> 4;
  const int f     = blockIdx.z & 15;
  const float* src;
  unsigned short* dst;
  int K, N, bx = blockIdx.x;
  if (which == 0)      { src = fc1_w; dst = fc1t; K = ND; N = NH; }
  else if (which == 1) { src = fc2_w; dst = fc2t; K = NH; N = ND; }
  else                 { src = glu_w; dst = glut; K = ND; N = N2D;
                         bx += (which == 3) ? 8 : 0; }
  if (bx * 32 >= N) return;
  const float* s = src + (size_t)f * K * N;
  unsigned short* d = dst + (size_t)f * K * N;
  const int k0 = blockIdx.y * 32, n0 = bx * 32;
  const int tx = threadIdx.x, ty = threadIdx.y;
#pragma unroll
  for (int i = 0; i < 32; i += 8)
    tile[ty + i][tx] = s[(size_t)(k0 + ty + i) * N + n0 + tx];
  __syncthreads();
#pragma unroll
  for (int i = 0; i < 32; i += 8)
    d[(size_t)(n0 + ty + i) * K + k0 + tx] = f2bf(tile[tx][ty + i]);
}

// ---------------------------------------------------------------------------
// G1: y1 = elu(h0 @ fc1^T + b). 256 thr (4 waves x 64 cols), BM=64,
// 4 m-tiles/block. h0 computed into LDS [64][264]; B read direct global->VGPR
// per kt (L2-resident panel, line-dense gather). 2 barriers/tile; copyout
// overlapped with next tile's h0 build.
// ---------------------------------------------------------------------------
__global__ __launch_bounds__(256, 2) void g1_kernel(
    const float* __restrict__ x, const float* __restrict__ w1,
    const float* __restrict__ b1, const unsigned short* __restrict__ fc1t,
    const float* __restrict__ fc1_b, unsigned short* __restrict__ y1) {
  __shared__ __align__(16) unsigned short h0buf[64 * 264];
  __shared__ __align__(16) unsigned short cbuf[64 * 264];
  const int tid = threadIdx.x, lane = tid & 63, wid = tid >> 6;
  const int rl = lane & 15, kc = lane >> 4;
  const int f = blockIdx.y;
  const unsigned short* Bf = fc1t + (size_t)f * NH * ND;  // [N][K]
  const float* w1f = w1 + f * ND;
  const float* b1f = b1 + f * ND;
  const int wn = wid * 64;

  float bias[4];
#pragma unroll
  for (int n = 0; n < 4; ++n) bias[n] = fc1_b[f * NH + wn + n * 16 + rl];

  const int cc = (tid & 31) * 8;
  const float4 wva = *(const float4*)(w1f + cc);
  const float4 wvb = *(const float4*)(w1f + cc + 4);
  const float4 bva = *(const float4*)(b1f + cc);
  const float4 bvb = *(const float4*)(b1f + cc + 4);

  f32x4 acc[4][4];

  for (int t = 0; t <= 4; ++t) {
    if (t) {  // epilogue of tile t-1 -> cbuf
#pragma unroll
      for (int n = 0; n < 4; ++n) {
        int c = wn + n * 16 + rl;
#pragma unroll
        for (int m = 0; m < 4; ++m)
#pragma unroll
          for (int j = 0; j < 4; ++j) {
            float v = acc[m][n][j] + bias[n];
            v = v > 0.f ? v : expm1f(v);
            cbuf[(m * 16 + kc * 4 + j) * 264 + c] = f2bf(v);
          }
      }
    }
    __syncthreads();
    if (t < 4) {  // build h0 tile t
      const int m0 = (blockIdx.x * 4 + t) * 64;
#pragma unroll
      for (int i = 0; i < 8; ++i) {
        int row = (tid >> 5) + i * 8;
        float xv = x[(size_t)(m0 + row) * NF + f];
        u16x8 o;
        o[0] = f2bf(fmaxf(fmaf(xv, wva.x, bva.x), 0.f));
        o[1] = f2bf(fmaxf(fmaf(xv, wva.y, bva.y), 0.f));
        o[2] = f2bf(fmaxf(fmaf(xv, wva.z, bva.z), 0.f));
        o[3] = f2bf(fmaxf(fmaf(xv, wva.w, bva.w), 0.f));
        o[4] = f2bf(fmaxf(fmaf(xv, wvb.x, bvb.x), 0.f));
        o[5] = f2bf(fmaxf(fmaf(xv, wvb.y, bvb.y), 0.f));
        o[6] = f2bf(fmaxf(fmaf(xv, wvb.z, bvb.z), 0.f));
        o[7] = f2bf(fmaxf(fmaf(xv, wvb.w, bvb.w), 0.f));
        *(u16x8*)(h0buf + row * 264 + cc) = o;
      }
    }
    if (t) {  // copyout tile t-1
      const int m0p = (blockIdx.x * 4 + t - 1) * 64;
#pragma unroll
      for (int v = 0; v < 8; ++v) {
        int job = tid + 256 * v;
        int row = job >> 5, ch = job & 31;
        u16x8 val = *(const u16x8*)(cbuf + row * 264 + ch * 8);
        *(u16x8*)(y1 + ((size_t)f * NBT + m0p + row) * NH + ch * 8) = val;
      }
    }
    __syncthreads();
    if (t < 4) {  // compute tile t
#pragma unroll
      for (int m = 0; m < 4; ++m)
#pragma unroll
        for (int n = 0; n < 4; ++n) acc[m][n] = (f32x4){0.f, 0.f, 0.f, 0.f};
#pragma unroll
      for (int kt = 0; kt < 8; ++kt) {
        bf16x8 av[4], bv[4];
#pragma unroll
        for (int n = 0; n < 4; ++n)
          bv[n] = *(const bf16x8*)(Bf + (size_t)(wn + n * 16 + rl) * ND +
                                   kt * 32 + kc * 8);
#pragma unroll
        for (int m = 0; m < 4; ++m)
          av[m] = *(const bf16x8*)(h0buf + (m * 16 + rl) * 264 + kt * 32 +
                                   kc * 8);
#pragma unroll
        for (int m = 0; m < 4; ++m)
#pragma unroll
          for (int n = 0; n < 4; ++n)
            acc[m][n] = __builtin_amdgcn_mfma_f32_16x16x32_bf16(
                av[m], bv[n], acc[m][n], 0, 0, 0);
      }
    }
  }
}

// ---------------------------------------------------------------------------
// G2: y2 = y1 @ fc2^T + b. 256 thr (4 waves x 64 cols), BM=64, 4 tiles/block.
// A staged per m-tile via gload_lds (linear dest + inv-swz source, validated);
// B direct global->VGPR per kt. 2 barriers/tile; gload drain covered by
// copyout of previous tile.
// ---------------------------------------------------------------------------
__global__ __launch_bounds__(256, 2) void g2_kernel(
    const unsigned short* __restrict__ y1,
    const unsigned short* __restrict__ fc2t, const float* __restrict__ fc2_b,
    unsigned short* __restrict__ y2) {
  __shared__ __align__(16) unsigned short Abuf[64 * 256];
  __shared__ __align__(16) unsigned short cbuf[64 * 264];
  const int tid = threadIdx.x, lane = tid & 63, wid = tid >> 6;
  const int rl = lane & 15, kc = lane >> 4;
  const int f = blockIdx.y;
  const unsigned short* Bf = fc2t + (size_t)f * ND * NH;  // [N][K]
  const int wn = wid * 64;

  float bias[4];
#pragma unroll
  for (int n = 0; n < 4; ++n) bias[n] = fc2_b[f * ND + wn + n * 16 + rl];

  f32x4 acc[4][4];

  for (int t = 0; t <= 4; ++t) {
    if (t) {
#pragma unroll
      for (int n = 0; n < 4; ++n) {
        int c = wn + n * 16 + rl;
#pragma unroll
        for (int m = 0; m < 4; ++m)
#pragma unroll
          for (int j = 0; j < 4; ++j)
            cbuf[(m * 16 + kc * 4 + j) * 264 + c] = f2bf(acc[m][n][j] + bias[n]);
      }
    }
    __syncthreads();
    if (t < 4) {  // stage A tile t: [64][256], 2048 granules, 8/thread
      const int m0 = (blockIdx.x * 4 + t) * 64;
      const unsigned short* Af = y1 + ((size_t)f * NBT + m0) * NH;
#pragma unroll
      for (int i = 0; i < 8; ++i) {
        int s = tid + 256 * i;
        int row = s >> 5, sl = s & 31;
        int srcg = (sl & 24) | ((sl ^ row) & 7);
        GLOAD16(Af + (size_t)row * NH + srcg * 8,
                (char*)Abuf + (wid * 64 + 256 * i) * 16);
      }
    }
    if (t) {
      const int m0p = (blockIdx.x * 4 + t - 1) * 64;
#pragma unroll
      for (int v = 0; v < 8; ++v) {
        int job = tid + 256 * v;
        int row = job >> 5, ch = job & 31;
        u16x8 val = *(const u16x8*)(cbuf + row * 264 + ch * 8);
        *(u16x8*)(y2 + ((size_t)f * NBT + m0p + row) * ND + ch * 8) = val;
      }
    }
    __syncthreads();  // drains vmcnt: A tile ready
    if (t < 4) {
#pragma unroll
      for (int m = 0; m < 4; ++m)
#pragma unroll
        for (int n = 0; n < 4; ++n) acc[m][n] = (f32x4){0.f, 0.f, 0.f, 0.f};
#pragma unroll
      for (int kt = 0; kt < 8; ++kt) {
        bf16x8 av[4], bv[4];
#pragma unroll
        for (int n = 0; n < 4; ++n)
          bv[n] = *(const bf16x8*)(Bf + (size_t)(wn + n * 16 + rl) * NH +
                                   kt * 32 + kc * 8);
#pragma unroll
        for (int m = 0; m < 4; ++m) {
          int row = m * 16 + rl;
          int gr = kt * 4 + kc;
          int g2 = (gr & 24) | ((gr ^ row) & 7);
          av[m] = *(const bf16x8*)(Abuf + row * 256 + g2 * 8);
        }
#pragma unroll
        for (int m = 0; m < 4; ++m)
#pragma unroll
          for (int n = 0; n < 4; ++n)
            acc[m][n] = __builtin_amdgcn_mfma_f32_16x16x32_bf16(
                av[m], bv[n], acc[m][n], 0, 0, 0);
      }
    }
  }
}

// ---------------------------------------------------------------------------
// G3: a|gate = y2 @ glu^T + b; v = h0 + a*sig(gate); LN -> H.
// 512 thr, 8 waves each owning 32 a-cols + paired 32 gate-cols (in-register
// GLU, validated round 4). A staged per m-tile (gload_lds), B direct
// global->VGPR. 8 tiles/block, 2 barriers/tile, copyout 2-deep pipelined.
// ---------------------------------------------------------------------------
__global__ __launch_bounds__(512, 2) void g3_kernel(
    const unsigned short* __restrict__ y2,
    const unsigned short* __restrict__ glut, const float* __restrict__ glu_b,
    const float* __restrict__ x, const float* __restrict__ w1,
    const float* __restrict__ b1, const float* __restrict__ ln_g,
    const float* __restrict__ ln_b, unsigned short* __restrict__ H) {
  __shared__ __align__(16) unsigned short Abuf[64 * 256];
  __shared__ __align__(16) unsigned short vbuf[64 * 264];
  __shared__ float xw[64];
  __shared__ float2 sums[8][64];
  __shared__ float2 sums2[64];
  const int tid = threadIdx.x, lane = tid & 63, wid = tid >> 6;
  const int rl = lane & 15, rq = lane >> 4;
  const int f = blockIdx.y;
  const unsigned short* Bf = glut + (size_t)f * ND * N2D;  // [512][256]
  const int colb = wid * 32;

  float w1c[2], b1c[2], ab_[2], gb_[2], lg[2], lb[2];
#pragma unroll
  for (int n = 0; n < 2; ++n) {
    int cA = colb + n * 16 + rl;
    w1c[n] = w1[f * ND + cA];
    b1c[n] = b1[f * ND + cA];
    ab_[n] = glu_b[f * N2D + cA];
    gb_[n] = glu_b[f * N2D + 256 + cA];
    lg[n] = ln_g[f * ND + cA];
    lb[n] = ln_b[f * ND + cA];
  }

  f32x4 acc[4][4];

  for (int t = 0; t <= 9; ++t) {
    // P1: GLU + row-sums for tile t-1
    if (t >= 1 && t <= 8) {
#pragma unroll
      for (int n = 0; n < 2; ++n) {
#pragma unroll
        for (int m = 0; m < 4; ++m)
#pragma unroll
          for (int j = 0; j < 4; ++j) {
            int r = m * 16 + rq * 4 + j;
            float a = acc[m][n][j] + ab_[n];
            float g = acc[m][n + 2][j] + gb_[n];
            float sg = 1.f / (1.f + __expf(-g));
            float h0 = fmaxf(fmaf(xw[r], w1c[n], b1c[n]), 0.f);
            acc[m][n][j] = fmaf(a, sg, h0);
          }
      }
#pragma unroll
      for (int m = 0; m < 4; ++m) {
#pragma unroll
        for (int j = 0; j < 4; ++j) {
          float s = acc[m][0][j] + acc[m][1][j];
          float q = fmaf(acc[m][0][j], acc[m][0][j],
                         acc[m][1][j] * acc[m][1][j]);
#pragma unroll
          for (int off = 1; off < 16; off <<= 1) {
            s += __shfl_xor(s, off);
            q += __shfl_xor(q, off);
          }
          if (rl == 0) sums[wid][m * 16 + rq * 4 + j] = make_float2(s, q);
        }
      }
    }
    __syncthreads();
    // P2: issue A-stage(t) + xw(t); copyout tile t-2; sums2 for tile t-1
    if (t < 8) {
      const int m0 = (blockIdx.x * 8 + t) * 64;
      const unsigned short* Af = y2 + ((size_t)f * NBT + m0) * ND;
#pragma unroll
      for (int i = 0; i < 4; ++i) {
        int s = tid + 512 * i;
        int row = s >> 5, sl = s & 31;
        int srcg = (sl & 24) | ((sl ^ row) & 7);
        GLOAD16(Af + (size_t)row * ND + srcg * 8,
                (char*)Abuf + (wid * 64 + 512 * i) * 16);
      }
      if (tid < 64) xw[tid] = x[(size_t)(m0 + tid) * NF + f];
    }
    if (t >= 2) {
      const int m0c = (blockIdx.x * 8 + t - 2) * 64;
#pragma unroll
      for (int v = 0; v < 4; ++v) {
        int job = tid + 512 * v;
        int row = job >> 5, ch = job & 31;
        u16x8 val = *(const u16x8*)(vbuf + row * 264 + ch * 8);
        *(u16x8*)(H + ((size_t)f * NBT + m0c + row) * ND + ch * 8) = val;
      }
    }
    if (t >= 1 && t <= 8 && tid < 64) {
      float tot = 0.f, tot2 = 0.f;
#pragma unroll
      for (int wv = 0; wv < 8; ++wv) {
        float2 p = sums[wv][tid];
        tot += p.x;
        tot2 += p.y;
      }
      float mean = tot * (1.f / 256.f);
      float var  = tot2 * (1.f / 256.f) - mean * mean;
      sums2[tid] = make_float2(mean, rsqrtf(var + 1e-5f));
    }
    __syncthreads();  // sums2 + A(t) ready (vmcnt drained, covered by copyout)
    // P3: LN(t-1) -> vbuf; compute(t)
    if (t >= 1 && t <= 8) {
#pragma unroll
      for (int n = 0; n < 2; ++n) {
        int cA = colb + n * 16 + rl;
#pragma unroll
        for (int m = 0; m < 4; ++m)
#pragma unroll
          for (int j = 0; j < 4; ++j) {
            int r = m * 16 + rq * 4 + j;
            float2 mr = sums2[r];
            vbuf[r * 264 + cA] =
                f2bf(fmaf((acc[m][n][j] - mr.x) * mr.y, lg[n], lb[n]));
          }
      }
    }
    if (t < 8) {
#pragma unroll
      for (int m = 0; m < 4; ++m)
#pragma unroll
        for (int n = 0; n < 4; ++n) acc[m][n] = (f32x4){0.f, 0.f, 0.f, 0.f};
#pragma unroll
      for (int kt = 0; kt < 8; ++kt) {
        bf16x8 av[4], bv[4];
#pragma unroll
        for (int n = 0; n < 4; ++n) {
          int brow = (n < 2) ? (colb + n * 16 + rl)
                             : (256 + colb + (n - 2) * 16 + rl);
          bv[n] = *(const bf16x8*)(Bf + (size_t)brow * ND + kt * 32 + rq * 8);
        }
#pragma unroll
        for (int m = 0; m < 4; ++m) {
          int row = m * 16 + rl;
          int gr = kt * 4 + rq;
          int g2 = (gr & 24) | ((gr ^ row) & 7);
          av[m] = *(const bf16x8*)(Abuf + row * 256 + g2 * 8);
        }
#pragma unroll
        for (int m = 0; m < 4; ++m)
#pragma unroll
          for (int n = 0; n < 4; ++n)
            acc[m][n] = __builtin_amdgcn_mfma_f32_16x16x32_bf16(
                av[m], bv[n], acc[m][n], 0, 0, 0);
      }
    }
  }
}

// ---------------------------------------------------------------------------
// z[bt][d] = sum_f H[f][bt][d] * w[bt][f]  (validated round 1)
// ---------------------------------------------------------------------------
__global__ __launch_bounds__(256) void combine_kernel(
    const unsigned short* __restrict__ H, const float* __restrict__ w,
    float* __restrict__ z) {
  int idx = blockIdx.x * 256 + threadIdx.x;
  int bt = idx >> 5;
  int d  = (idx & 31) << 3;
  float a[8];
#pragma unroll
  for (int j = 0; j < 8; ++j) a[j] = 0.f;
#pragma unroll
  for (int f = 0; f < 16; ++f) {
    u16x8 hv = *(const u16x8*)(H + ((size_t)f * NBT + bt) * ND + d);
    float wvv = w[bt * 16 + f];
#pragma unroll
    for (int j = 0; j < 8; ++j) a[j] = fmaf(bf2f(hv[j]), wvv, a[j]);
  }
  float4 o0 = {a[0], a[1], a[2], a[3]};
  float4 o1 = {a[4], a[5], a[6], a[7]};
  *(float4*)(z + (size_t)bt * ND + d)     = o0;
  *(float4*)(z + (size_t)bt * ND + d + 4) = o1;
}

// ---------------------------------------------------------------------------
extern "C" void kernel_launch(void* const* d_in, const int* in_sizes, int n_in,
                              void* d_out, int out_size, void* d_ws,
                              size_t ws_size, hipStream_t stream) {
  const float* x        = (const float*)d_in[0];
  const float* w1       = (const float*)d_in[1];
  const float* b1       = (const float*)d_in[2];
  const float* fc1_w    = (const float*)d_in[3];
  const float* fc1_b    = (const float*)d_in[4];
  const float* fc2_w    = (const float*)d_in[5];
  const float* fc2_b    = (const float*)d_in[6];
  const float* glu_w    = (const float*)d_in[7];
  const float* glu_b    = (const float*)d_in[8];
  const float* ln_g     = (const float*)d_in[9];
  const float* ln_b     = (const float*)d_in[10];
  const float* wg_fc1_w = (const float*)d_in[11];
  const float* wg_fc1_b = (const float*)d_in[12];
  const float* wg_fc2_w = (const float*)d_in[13];
  const float* wg_fc2_b = (const float*)d_in[14];
  const float* wg_glu_w = (const float*)d_in[15];
  const float* wg_glu_b = (const float*)d_in[16];
  const float* wg_ln_g  = (const float*)d_in[17];
  const float* wg_ln_b  = (const float*)d_in[18];

  char* ws = (char*)d_ws;
  unsigned short* fc1t = (unsigned short*)ws;                       // 2 MB
  unsigned short* fc2t = fc1t + (size_t)NF * NH * ND;               // 2 MB
  unsigned short* glut = fc2t + (size_t)NF * ND * NH;               // 4 MB
  unsigned short* y1   = (unsigned short*)(ws + (8ull << 20));      // 64 MiB
  unsigned short* y2   = (unsigned short*)(ws + (72ull << 20));     // 64 MiB
  unsigned short* Hbuf = (unsigned short*)(ws + (136ull << 20));    // 64 MiB

  float* zout = (float*)d_out;                 // [NBT][ND]
  float* wout = zout + (size_t)NBT * ND;       // [NBT][16]

  wgrn_kernel<<<256, 256, 0, stream>>>(x, wg_fc1_w, wg_fc1_b, wg_fc2_w,
                                       wg_fc2_b, wg_glu_w, wg_glu_b, wg_ln_g,
                                       wg_ln_b, wout);
  transpose_all<<<dim3(16, 8, 64), dim3(32, 8), 0, stream>>>(
      fc1_w, fc2_w, glu_w, fc1t, fc2t, glut);

  g1_kernel<<<dim3(32, 16), 256, 0, stream>>>(x, w1, b1, fc1t, fc1_b, y1);
  g2_kernel<<<dim3(32, 16), 256, 0, stream>>>(y1, fc2t, fc2_b, y2);
  g3_kernel<<<dim3(16, 16), 512, 0, stream>>>(y2, glut, glu_b, x, w1, b1,
                                              ln_g, ln_b, Hbuf);
  combine_kernel<<<(NBT * ND / 8) / 256, 256, 0, stream>>>(Hbuf, wout, zout);

  (void)in_sizes; (void)n_in; (void)out_size; (void)ws_size;
}

// Round 8
// 242.169 us; speedup vs baseline: 1.1273x; 1.0959x over previous
//
#include <hip/hip_runtime.h>
#include <hip/hip_bf16.h>

#define NBT 8192      // B*T
#define NF  16
#define ND  256
#define NH  256
#define N2D 512

typedef short bf16x8 __attribute__((ext_vector_type(8)));
typedef float f32x4 __attribute__((ext_vector_type(4)));
typedef unsigned short u16x8 __attribute__((ext_vector_type(8)));

__device__ __forceinline__ float bf2f(unsigned short u) {
  return __uint_as_float(((unsigned)u) << 16);
}
__device__ __forceinline__ unsigned short f2bf(float f) {
  unsigned u = __float_as_uint(f);
  return (unsigned short)((u + 0x7FFFu + ((u >> 16) & 1u)) >> 16);
}

#define GLOAD16(src, dst)                                                     \
  __builtin_amdgcn_global_load_lds(                                           \
      (const __attribute__((address_space(1))) unsigned int*)(src),           \
      (__attribute__((address_space(3))) unsigned int*)(dst), 16, 0, 0)

// counted-wait pipeline barrier: waits only this wave's outstanding ops AFTER
// compute, so STAGE(t+1) issued before COMPUTE(t) stays in flight during it.
#define PIPE_SYNC()                                                           \
  do {                                                                        \
    asm volatile("s_waitcnt vmcnt(0) lgkmcnt(0)" ::: "memory");               \
    __builtin_amdgcn_s_barrier();                                             \
    __builtin_amdgcn_sched_barrier(0);                                        \
  } while (0)

// ---------------------------------------------------------------------------
// Weight GRN + softmax -> w [NBT][16] (fp32 exact; validated round 1)
// ---------------------------------------------------------------------------
__global__ __launch_bounds__(256) void wgrn_kernel(
    const float* __restrict__ x, const float* __restrict__ fw1,
    const float* __restrict__ fb1, const float* __restrict__ fw2,
    const float* __restrict__ fb2, const float* __restrict__ gwt,
    const float* __restrict__ gbt, const float* __restrict__ lng,
    const float* __restrict__ lnb, float* __restrict__ wout) {
  __shared__ float w1t[256 * 16];
  __shared__ float w2s[256 * 16];
  const int tid = threadIdx.x;
  for (int i = tid; i < 4096; i += 256) {
    int ff = i >> 8, j = i & 255;
    w1t[j * 16 + ff] = fw1[i];
    w2s[i] = fw2[i];
  }
  __syncthreads();
  const int sub  = tid & 7;
  const int rowi = tid >> 3;
  const int bt   = blockIdx.x * 32 + rowi;
  float xr[16];
#pragma unroll
  for (int i = 0; i < 4; ++i)
    *(float4*)&xr[i * 4] = *(const float4*)(x + (size_t)bt * 16 + i * 4);
  float acc2[16];
#pragma unroll
  for (int q = 0; q < 16; ++q) acc2[q] = 0.f;
  for (int j = sub; j < 256; j += 8) {
    float h = fb1[j];
    const float* wr = &w1t[j * 16];
#pragma unroll
    for (int q = 0; q < 16; ++q) h = fmaf(xr[q], wr[q], h);
    h = h > 0.f ? h : expm1f(h);
    const float* w2r = &w2s[j * 16];
#pragma unroll
    for (int q = 0; q < 16; ++q) acc2[q] = fmaf(h, w2r[q], acc2[q]);
  }
#pragma unroll
  for (int off = 1; off < 8; off <<= 1) {
#pragma unroll
    for (int q = 0; q < 16; ++q) acc2[q] += __shfl_xor(acc2[q], off);
  }
#pragma unroll
  for (int q = 0; q < 16; ++q) acc2[q] += fb2[q];
  float gw[32];
#pragma unroll
  for (int k = 0; k < 32; ++k) {
    float s = gbt[k];
#pragma unroll
    for (int q = 0; q < 16; ++q) s = fmaf(acc2[q], gwt[q * 32 + k], s);
    gw[k] = s;
  }
  float v[16];
  float mean = 0.f;
#pragma unroll
  for (int q = 0; q < 16; ++q) {
    float sg = 1.f / (1.f + __expf(-gw[16 + q]));
    v[q] = fmaf(gw[q], sg, xr[q]);
    mean += v[q];
  }
  mean *= (1.f / 16.f);
  float var = 0.f;
#pragma unroll
  for (int q = 0; q < 16; ++q) { float d = v[q] - mean; var = fmaf(d, d, var); }
  var *= (1.f / 16.f);
  float rstd = rsqrtf(var + 1e-5f);
  float mx = -1e30f;
#pragma unroll
  for (int q = 0; q < 16; ++q) {
    v[q] = (v[q] - mean) * rstd * lng[q] + lnb[q];
    mx = fmaxf(mx, v[q]);
  }
  float se = 0.f;
#pragma unroll
  for (int q = 0; q < 16; ++q) { v[q] = __expf(v[q] - mx); se += v[q]; }
  float inv = 1.f / se;
  if (sub == 0) {
#pragma unroll
    for (int i = 0; i < 4; ++i) {
      float4 o = { v[i*4+0]*inv, v[i*4+1]*inv, v[i*4+2]*inv, v[i*4+3]*inv };
      *(float4*)(wout + (size_t)bt * 16 + i * 4) = o;
    }
  }
}

// ---------------------------------------------------------------------------
// Fused weight prep: fp32 [K][N] -> bf16 [N][K] (validated round 5)
// ---------------------------------------------------------------------------
__global__ void transpose_all(const float* __restrict__ fc1_w,
                              const float* __restrict__ fc2_w,
                              const float* __restrict__ glu_w,
                              unsigned short* __restrict__ fc1t,
                              unsigned short* __restrict__ fc2t,
                              unsigned short* __restrict__ glut) {
  __shared__ float tile[32][33];
  const int which = blockIdx.z >> 4;
  const int f     = blockIdx.z & 15;
  const float* src;
  unsigned short* dst;
  int K, N, bx = blockIdx.x;
  if (which == 0)      { src = fc1_w; dst = fc1t; K = ND; N = NH; }
  else if (which == 1) { src = fc2_w; dst = fc2t; K = NH; N = ND; }
  else                 { src = glu_w; dst = glut; K = ND; N = N2D;
                         bx += (which == 3) ? 8 : 0; }
  if (bx * 32 >= N) return;
  const float* s = src + (size_t)f * K * N;
  unsigned short* d = dst + (size_t)f * K * N;
  const int k0 = blockIdx.y * 32, n0 = bx * 32;
  const int tx = threadIdx.x, ty = threadIdx.y;
#pragma unroll
  for (int i = 0; i < 32; i += 8)
    tile[ty + i][tx] = s[(size_t)(k0 + ty + i) * N + n0 + tx];
  __syncthreads();
#pragma unroll
  for (int i = 0; i < 32; i += 8)
    d[(size_t)(n0 + ty + i) * K + k0 + tx] = f2bf(tile[tx][ty + i]);
}

// ---------------------------------------------------------------------------
// G1: y1 = elu(h0 @ fc1^T + b). BM=128, BN=128, 256 thr (4 waves 2x2).
// BK=32 dbuf pipeline: STAGE(t+1) before COMPUTE(t), PIPE_SYNC per step.
// h0 computed by VALU into padded dbuf (stride 40); B via gload_lds+swizzle.
// ---------------------------------------------------------------------------
__global__ __launch_bounds__(256, 2) void g1_kernel(
    const float* __restrict__ x, const float* __restrict__ w1,
    const float* __restrict__ b1, const unsigned short* __restrict__ fc1t,
    const float* __restrict__ fc1_b, unsigned short* __restrict__ y1) {
  __shared__ __align__(16) unsigned short h0b[2][128 * 40];  // 20480 B
  __shared__ __align__(16) unsigned short bb[2][128 * 32];   // 16384 B
  __shared__ __align__(16) unsigned short cbuf[128 * 136];   // 34816 B
  __shared__ float xw[128];
  const int tid = threadIdx.x, lane = tid & 63, wid = tid >> 6;
  const int rl = lane & 15, kc = lane >> 4;
  const int f = blockIdx.z, m0 = blockIdx.y * 128, n0 = blockIdx.x * 128;
  const unsigned short* Bf = fc1t + (size_t)f * NH * ND;  // [N][K]
  const float* w1f = w1 + f * ND;
  const float* b1f = b1 + f * ND;
  const int wm = (wid >> 1) * 64, wn = (wid & 1) * 64;

  float bias[4];
#pragma unroll
  for (int n = 0; n < 4; ++n) bias[n] = fc1_b[f * NH + n0 + wn + n * 16 + rl];

  auto stage_B = [&](int kt, int buf) {
#pragma unroll
    for (int i = 0; i < 2; ++i) {
      int s = tid + 256 * i;
      int row = s >> 2, sl = s & 3;
      int srcg = sl ^ ((row >> 1) & 3);
      GLOAD16(Bf + (size_t)(n0 + row) * ND + kt + srcg * 8,
              (char*)bb[buf] + s * 16);
    }
  };
  auto build_h0 = [&](int kt, int buf) {
#pragma unroll
    for (int i = 0; i < 2; ++i) {
      int job = tid + 256 * i;
      int row = job >> 2, c8 = job & 3, c = kt + c8 * 8;
      float xv = xw[row];
      float4 wa = *(const float4*)(w1f + c);
      float4 wb = *(const float4*)(w1f + c + 4);
      float4 ba = *(const float4*)(b1f + c);
      float4 bc = *(const float4*)(b1f + c + 4);
      u16x8 o;
      o[0] = f2bf(fmaxf(fmaf(xv, wa.x, ba.x), 0.f));
      o[1] = f2bf(fmaxf(fmaf(xv, wa.y, ba.y), 0.f));
      o[2] = f2bf(fmaxf(fmaf(xv, wa.z, ba.z), 0.f));
      o[3] = f2bf(fmaxf(fmaf(xv, wa.w, ba.w), 0.f));
      o[4] = f2bf(fmaxf(fmaf(xv, wb.x, bc.x), 0.f));
      o[5] = f2bf(fmaxf(fmaf(xv, wb.y, bc.y), 0.f));
      o[6] = f2bf(fmaxf(fmaf(xv, wb.z, bc.z), 0.f));
      o[7] = f2bf(fmaxf(fmaf(xv, wb.w, bc.w), 0.f));
      *(u16x8*)(h0b[buf] + row * 40 + c8 * 8) = o;
    }
  };

  f32x4 acc[4][4];
#pragma unroll
  for (int m = 0; m < 4; ++m)
#pragma unroll
    for (int n = 0; n < 4; ++n) acc[m][n] = (f32x4){0.f, 0.f, 0.f, 0.f};

  if (tid < 128) xw[tid] = x[(size_t)(m0 + tid) * NF + f];
  stage_B(0, 0);
  __syncthreads();  // xw visible
  build_h0(0, 0);
  PIPE_SYNC();

#pragma unroll
  for (int t = 0; t < 8; ++t) {
    int cur = t & 1;
    if (t < 7) {
      stage_B((t + 1) * 32, cur ^ 1);
      build_h0((t + 1) * 32, cur ^ 1);
    }
    // compute(cur)
    bf16x8 av[4];
#pragma unroll
    for (int m = 0; m < 4; ++m)
      av[m] = *(const bf16x8*)(h0b[cur] + (wm + m * 16 + rl) * 40 + kc * 8);
#pragma unroll
    for (int n = 0; n < 4; ++n) {
      int r = wn + n * 16 + rl;
      int g = kc ^ ((r >> 1) & 3);
      bf16x8 bv = *(const bf16x8*)((const char*)bb[cur] + r * 64 + g * 16);
#pragma unroll
      for (int m = 0; m < 4; ++m)
        acc[m][n] =
            __builtin_amdgcn_mfma_f32_16x16x32_bf16(av[m], bv, acc[m][n], 0, 0, 0);
    }
    PIPE_SYNC();
  }

  // bounce epilogue (validated round 4)
#pragma unroll
  for (int n = 0; n < 4; ++n) {
    int c = wn + n * 16 + rl;
#pragma unroll
    for (int m = 0; m < 4; ++m)
#pragma unroll
      for (int j = 0; j < 4; ++j) {
        float v = acc[m][n][j] + bias[n];
        v = v > 0.f ? v : expm1f(v);
        cbuf[(m * 16 + kc * 4 + j + ((wm) ? 64 : 0)) * 136 + c] = f2bf(v);
      }
  }
  __syncthreads();
#pragma unroll
  for (int v = 0; v < 8; ++v) {
    int row = (tid >> 4) + v * 16, ch = tid & 15;
    u16x8 val = *(const u16x8*)(cbuf + row * 136 + ch * 8);
    *(u16x8*)(y1 + ((size_t)f * NBT + m0 + row) * NH + n0 + ch * 8) = val;
  }
}

// ---------------------------------------------------------------------------
// G2: y2 = y1 @ fc2^T + b. BM=128, BN=256(=N), 512 thr (8 waves 2x4).
// BK=32 dbuf pipeline, both operands gload_lds+swizzle. Two-pass bounce.
// ---------------------------------------------------------------------------
__global__ __launch_bounds__(512, 4) void g2_kernel(
    const unsigned short* __restrict__ y1,
    const unsigned short* __restrict__ fc2t, const float* __restrict__ fc2_b,
    unsigned short* __restrict__ y2) {
  __shared__ __align__(16) char arena[49152];  // Ab 2x8K | Bb 2x16K ; cbuf alias
  unsigned short* cbuf = (unsigned short*)arena;  // [128][136]
  const int tid = threadIdx.x, lane = tid & 63, wid = tid >> 6;
  const int rl = lane & 15, kc = lane >> 4;
  const int f = blockIdx.y, m0 = blockIdx.x * 128;
  const unsigned short* Af = y1 + (size_t)f * NBT * NH;
  const unsigned short* Bf = fc2t + (size_t)f * ND * NH;  // [N][K]
  const int wm = (wid >> 2) * 64, wn = (wid & 3) * 64;

  float bias[4];
#pragma unroll
  for (int n = 0; n < 4; ++n) bias[n] = fc2_b[f * ND + wn + n * 16 + rl];

  auto stage = [&](int kt, int buf) {
    char* Ab = arena + buf * 8192;
    char* Bb = arena + 16384 + buf * 16384;
    {
      int s = tid;  // A: 512 granules
      int row = s >> 2, sl = s & 3;
      int srcg = sl ^ ((row >> 1) & 3);
      GLOAD16(Af + (size_t)(m0 + row) * NH + kt + srcg * 8, Ab + s * 16);
    }
#pragma unroll
    for (int i = 0; i < 2; ++i) {  // B: 1024 granules
      int s = tid + 512 * i;
      int row = s >> 2, sl = s & 3;
      int srcg = sl ^ ((row >> 1) & 3);
      GLOAD16(Bf + (size_t)row * NH + kt + srcg * 8, Bb + s * 16);
    }
  };

  f32x4 acc[4][4];
#pragma unroll
  for (int m = 0; m < 4; ++m)
#pragma unroll
    for (int n = 0; n < 4; ++n) acc[m][n] = (f32x4){0.f, 0.f, 0.f, 0.f};

  stage(0, 0);
  PIPE_SYNC();
#pragma unroll
  for (int t = 0; t < 8; ++t) {
    int cur = t & 1;
    if (t < 7) stage((t + 1) * 32, cur ^ 1);
    const char* Ab = arena + cur * 8192;
    const char* Bb = arena + 16384 + cur * 16384;
    bf16x8 av[4];
#pragma unroll
    for (int m = 0; m < 4; ++m) {
      int r = wm + m * 16 + rl;
      int g = kc ^ ((r >> 1) & 3);
      av[m] = *(const bf16x8*)(Ab + r * 64 + g * 16);
    }
#pragma unroll
    for (int n = 0; n < 4; ++n) {
      int rr = wn + n * 16 + rl;
      int g = kc ^ ((rr >> 1) & 3);
      bf16x8 bv = *(const bf16x8*)(Bb + rr * 64 + g * 16);
#pragma unroll
      for (int m = 0; m < 4; ++m)
        acc[m][n] =
            __builtin_amdgcn_mfma_f32_16x16x32_bf16(av[m], bv, acc[m][n], 0, 0, 0);
    }
    PIPE_SYNC();
  }

  // two-pass bounce epilogue (r4, + explicit barrier before aliased write)
  const int hsel = (wid & 3) >> 1;
#pragma unroll
  for (int h = 0; h < 2; ++h) {
    if (h) __syncthreads();
    if (hsel == h) {
#pragma unroll
      for (int n = 0; n < 4; ++n) {
        int c = wn + n * 16 + rl;
        int cl = c - h * 128;
#pragma unroll
        for (int m = 0; m < 4; ++m)
#pragma unroll
          for (int j = 0; j < 4; ++j)
            cbuf[(wm + m * 16 + kc * 4 + j) * 136 + cl] =
                f2bf(acc[m][n][j] + bias[n]);
      }
    }
    __syncthreads();
#pragma unroll
    for (int v = 0; v < 4; ++v) {
      int row = (tid >> 4) + v * 32, ch = tid & 15;
      u16x8 val = *(const u16x8*)(cbuf + row * 136 + ch * 8);
      *(u16x8*)(y2 + ((size_t)f * NBT + m0 + row) * ND + h * 128 + ch * 8) =
          val;
    }
  }
}

// ---------------------------------------------------------------------------
// G3: a|gate = y2 @ glu^T + b; v = h0 + a*sig(gate); LN -> H.
// BM=64, BN=512(=N), 512 thr; wave owns paired a/gate cols (r4 validated).
// BK=32 dbuf pipeline. vbuf bounce epilogue.
// ---------------------------------------------------------------------------
__global__ __launch_bounds__(512, 4) void g3_kernel(
    const unsigned short* __restrict__ y2,
    const unsigned short* __restrict__ glut, const float* __restrict__ glu_b,
    const float* __restrict__ x, const float* __restrict__ w1,
    const float* __restrict__ b1, const float* __restrict__ ln_g,
    const float* __restrict__ ln_b, unsigned short* __restrict__ H) {
  __shared__ __align__(16) char arena[73728];  // Ab 2x4K | Bb 2x32K ; vbuf alias
  __shared__ float xw[64];
  __shared__ float2 sums[8][64];
  __shared__ float2 sums2[64];
  unsigned short* vbuf = (unsigned short*)arena;  // [64][264]
  const int tid = threadIdx.x, lane = tid & 63, wid = tid >> 6;
  const int rl = lane & 15, rq = lane >> 4;
  const int f = blockIdx.y, m0 = blockIdx.x * 64;
  const unsigned short* Af = y2 + (size_t)f * NBT * ND;
  const unsigned short* Bf = glut + (size_t)f * ND * N2D;  // [512][256]
  const int colb = wid * 32;

  float w1c[2], b1c[2], ab_[2], gb_[2], lg[2], lb[2];
#pragma unroll
  for (int n = 0; n < 2; ++n) {
    int cA = colb + n * 16 + rl;
    w1c[n] = w1[f * ND + cA];
    b1c[n] = b1[f * ND + cA];
    ab_[n] = glu_b[f * N2D + cA];
    gb_[n] = glu_b[f * N2D + 256 + cA];
    lg[n] = ln_g[f * ND + cA];
    lb[n] = ln_b[f * ND + cA];
  }

  auto stage = [&](int kt, int buf) {
    char* Ab = arena + buf * 4096;
    char* Bb = arena + 8192 + buf * 32768;
    if (tid < 256) {  // A: 256 granules (waves 0-3)
      int s = tid;
      int row = s >> 2, sl = s & 3;
      int srcg = sl ^ ((row >> 1) & 3);
      GLOAD16(Af + (size_t)(m0 + row) * ND + kt + srcg * 8, Ab + s * 16);
    }
#pragma unroll
    for (int i = 0; i < 4; ++i) {  // B: 2048 granules
      int s = tid + 512 * i;
      int row = s >> 2, sl = s & 3;
      int srcg = sl ^ ((row >> 1) & 3);
      GLOAD16(Bf + (size_t)row * ND + kt + srcg * 8, Bb + s * 16);
    }
  };

  f32x4 acc[4][4];
#pragma unroll
  for (int m = 0; m < 4; ++m)
#pragma unroll
    for (int n = 0; n < 4; ++n) acc[m][n] = (f32x4){0.f, 0.f, 0.f, 0.f};

  if (tid < 64) xw[tid] = x[(size_t)(m0 + tid) * NF + f];
  stage(0, 0);
  PIPE_SYNC();
#pragma unroll
  for (int t = 0; t < 8; ++t) {
    int cur = t & 1;
    if (t < 7) stage((t + 1) * 32, cur ^ 1);
    const char* Ab = arena + cur * 4096;
    const char* Bb = arena + 8192 + cur * 32768;
    bf16x8 av[4];
#pragma unroll
    for (int m = 0; m < 4; ++m) {
      int r = m * 16 + rl;
      int g = rq ^ ((r >> 1) & 3);
      av[m] = *(const bf16x8*)(Ab + r * 64 + g * 16);
    }
#pragma unroll
    for (int n = 0; n < 4; ++n) {
      int brow = (n < 2) ? (colb + n * 16 + rl)
                         : (256 + colb + (n - 2) * 16 + rl);
      int g = rq ^ ((brow >> 1) & 3);
      bf16x8 bv = *(const bf16x8*)(Bb + brow * 64 + g * 16);
#pragma unroll
      for (int m = 0; m < 4; ++m)
        acc[m][n] =
            __builtin_amdgcn_mfma_f32_16x16x32_bf16(av[m], bv, acc[m][n], 0, 0, 0);
    }
    PIPE_SYNC();
  }

  // in-register GLU (validated round 4)
#pragma unroll
  for (int n = 0; n < 2; ++n) {
#pragma unroll
    for (int m = 0; m < 4; ++m) {
#pragma unroll
      for (int j = 0; j < 4; ++j) {
        int r = m * 16 + rq * 4 + j;
        float a = acc[m][n][j] + ab_[n];
        float g = acc[m][n + 2][j] + gb_[n];
        float sg = 1.f / (1.f + __expf(-g));
        float h0 = fmaxf(fmaf(xw[r], w1c[n], b1c[n]), 0.f);
        acc[m][n][j] = fmaf(a, sg, h0);
      }
    }
  }
  // row sums (mean/var over 256 cols)
#pragma unroll
  for (int m = 0; m < 4; ++m) {
#pragma unroll
    for (int j = 0; j < 4; ++j) {
      float s = acc[m][0][j] + acc[m][1][j];
      float q = fmaf(acc[m][0][j], acc[m][0][j], acc[m][1][j] * acc[m][1][j]);
#pragma unroll
      for (int off = 1; off < 16; off <<= 1) {
        s += __shfl_xor(s, off);
        q += __shfl_xor(q, off);
      }
      if (rl == 0) sums[wid][m * 16 + rq * 4 + j] = make_float2(s, q);
    }
  }
  __syncthreads();
  if (tid < 64) {
    float tot = 0.f, tot2 = 0.f;
#pragma unroll
    for (int wv = 0; wv < 8; ++wv) {
      float2 p = sums[wv][tid];
      tot += p.x;
      tot2 += p.y;
    }
    float mean = tot * (1.f / 256.f);
    float var  = tot2 * (1.f / 256.f) - mean * mean;
    sums2[tid] = make_float2(mean, rsqrtf(var + 1e-5f));
  }
  __syncthreads();
#pragma unroll
  for (int n = 0; n < 2; ++n) {
    int cA = colb + n * 16 + rl;
#pragma unroll
    for (int m = 0; m < 4; ++m) {
#pragma unroll
      for (int j = 0; j < 4; ++j) {
        int r = m * 16 + rq * 4 + j;
        float2 mr = sums2[r];
        vbuf[r * 264 + cA] =
            f2bf(fmaf((acc[m][n][j] - mr.x) * mr.y, lg[n], lb[n]));
      }
    }
  }
  __syncthreads();
#pragma unroll
  for (int v = 0; v < 4; ++v) {
    int job = tid + 512 * v;
    int row = job >> 5, ch = job & 31;
    u16x8 val = *(const u16x8*)(vbuf + row * 264 + ch * 8);
    *(u16x8*)(H + ((size_t)f * NBT + m0 + row) * ND + ch * 8) = val;
  }
}

// ---------------------------------------------------------------------------
// z[bt][d] = sum_f H[f][bt][d] * w[bt][f]  (validated round 1)
// ---------------------------------------------------------------------------
__global__ __launch_bounds__(256) void combine_kernel(
    const unsigned short* __restrict__ H, const float* __restrict__ w,
    float* __restrict__ z) {
  int idx = blockIdx.x * 256 + threadIdx.x;
  int bt = idx >> 5;
  int d  = (idx & 31) << 3;
  float a[8];
#pragma unroll
  for (int j = 0; j < 8; ++j) a[j] = 0.f;
#pragma unroll
  for (int f = 0; f < 16; ++f) {
    u16x8 hv = *(const u16x8*)(H + ((size_t)f * NBT + bt) * ND + d);
    float wvv = w[bt * 16 + f];
#pragma unroll
    for (int j = 0; j < 8; ++j) a[j] = fmaf(bf2f(hv[j]), wvv, a[j]);
  }
  float4 o0 = {a[0], a[1], a[2], a[3]};
  float4 o1 = {a[4], a[5], a[6], a[7]};
  *(float4*)(z + (size_t)bt * ND + d)     = o0;
  *(float4*)(z + (size_t)bt * ND + d + 4) = o1;
}

// ---------------------------------------------------------------------------
extern "C" void kernel_launch(void* const* d_in, const int* in_sizes, int n_in,
                              void* d_out, int out_size, void* d_ws,
                              size_t ws_size, hipStream_t stream) {
  const float* x        = (const float*)d_in[0];
  const float* w1       = (const float*)d_in[1];
  const float* b1       = (const float*)d_in[2];
  const float* fc1_w    = (const float*)d_in[3];
  const float* fc1_b    = (const float*)d_in[4];
  const float* fc2_w    = (const float*)d_in[5];
  const float* fc2_b    = (const float*)d_in[6];
  const float* glu_w    = (const float*)d_in[7];
  const float* glu_b    = (const float*)d_in[8];
  const float* ln_g     = (const float*)d_in[9];
  const float* ln_b     = (const float*)d_in[10];
  const float* wg_fc1_w = (const float*)d_in[11];
  const float* wg_fc1_b = (const float*)d_in[12];
  const float* wg_fc2_w = (const float*)d_in[13];
  const float* wg_fc2_b = (const float*)d_in[14];
  const float* wg_glu_w = (const float*)d_in[15];
  const float* wg_glu_b = (const float*)d_in[16];
  const float* wg_ln_g  = (const float*)d_in[17];
  const float* wg_ln_b  = (const float*)d_in[18];

  char* ws = (char*)d_ws;
  unsigned short* fc1t = (unsigned short*)ws;                       // 2 MB
  unsigned short* fc2t = fc1t + (size_t)NF * NH * ND;               // 2 MB
  unsigned short* glut = fc2t + (size_t)NF * ND * NH;               // 4 MB
  unsigned short* y1   = (unsigned short*)(ws + (8ull << 20));      // 64 MiB
  unsigned short* y2   = (unsigned short*)(ws + (72ull << 20));     // 64 MiB
  unsigned short* Hbuf = (unsigned short*)(ws + (136ull << 20));    // 64 MiB

  float* zout = (float*)d_out;                 // [NBT][ND]
  float* wout = zout + (size_t)NBT * ND;       // [NBT][16]

  wgrn_kernel<<<256, 256, 0, stream>>>(x, wg_fc1_w, wg_fc1_b, wg_fc2_w,
                                       wg_fc2_b, wg_glu_w, wg_glu_b, wg_ln_g,
                                       wg_ln_b, wout);
  transpose_all<<<dim3(16, 8, 64), dim3(32, 8), 0, stream>>>(
      fc1_w, fc2_w, glu_w, fc1t, fc2t, glut);

  g1_kernel<<<dim3(NH / 128, NBT / 128, NF), 256, 0, stream>>>(
      x, w1, b1, fc1t, fc1_b, y1);
  g2_kernel<<<dim3(NBT / 128, NF), 512, 0, stream>>>(y1, fc2t, fc2_b, y2);
  g3_kernel<<<dim3(NBT / 64, NF), 512, 0, stream>>>(y2, glut, glu_b, x, w1, b1,
                                                    ln_g, ln_b, Hbuf);
  combine_kernel<<<(NBT * ND / 8) / 256, 256, 0, stream>>>(Hbuf, wout, zout);

  (void)in_sizes; (void)n_in; (void)out_size; (void)ws_size;
}